// Round 13
// baseline (180.196 us; speedup 1.0000x reference)
//
#include <hip/hip_runtime.h>
#include <hip/hip_bf16.h>
#include <math.h>

#define DIM    384
#define NHEAD  8
#define HDIM   48
#define NTOK   2048              // tokens per batch (8*16*16)
#define BATCH  2
#define TOKS   (BATCH * NTOK)    // 4096
#define HIDDEN 1536

typedef __bf16 bf16x8 __attribute__((ext_vector_type(8)));
typedef float  f32x4  __attribute__((ext_vector_type(4)));
typedef unsigned short u16;

union bfu { __hip_bfloat16 h; u16 u; };

__device__ __forceinline__ void load_lds16(const void* g, void* l) {
    __builtin_amdgcn_global_load_lds(
        (const __attribute__((address_space(1))) void*)g,
        (__attribute__((address_space(3))) void*)l, 16, 0, 0);
}

// ---------------------------------------------------------------------------
// prep: Wqkv cast+transpose (blocks 0..431) + fused input transpose/LN1
// (blocks 432..559). Wo/W1/W2 transposes live in the QKV dispatch (R11).
// ---------------------------------------------------------------------------
__global__ __launch_bounds__(256) void prep(
    const float* __restrict__ Wqkv, __hip_bfloat16* __restrict__ WqkvT,
    const float* __restrict__ x, const float* __restrict__ g,
    const float* __restrict__ bta,
    float* __restrict__ hOut, __hip_bfloat16* __restrict__ y) {
    __shared__ __align__(16) char smem[384 * 33 * 4];
    int id = blockIdx.x;
    int tid = threadIdx.x;
    if (id < 432) {
        float (*t)[33] = (float(*)[33])smem;
        const int R = 384, C = 1152, tc = C / 32;
        int i0 = (id / tc) * 32, j0 = (id % tc) * 32;
        int tx = tid & 31, ty = tid >> 5;
#pragma unroll
        for (int k = 0; k < 32; k += 8)
            t[ty + k][tx] = Wqkv[(size_t)(i0 + ty + k) * C + j0 + tx];
        __syncthreads();
#pragma unroll
        for (int k = 0; k < 32; k += 8)
            WqkvT[(size_t)(j0 + ty + k) * R + i0 + tx] = __float2bfloat16(t[tx][ty + k]);
    } else {
        float* t = (float*)smem;
        int id2 = id - 432;
        int n0 = (id2 & 63) * 32, b = id2 >> 6;
        const float* xb = x + (size_t)b * DIM * NTOK;
        for (int idx = tid; idx < 384 * 32; idx += 256) {
            int c = idx >> 5, n = idx & 31;
            t[c * 33 + n] = xb[(size_t)c * NTOK + n0 + n];
        }
        __syncthreads();
        int wid = tid >> 6, lane = tid & 63;
#pragma unroll
        for (int it = 0; it < 8; ++it) {
            int tl = it * 4 + wid;
            float v[6];
            float s = 0.f;
#pragma unroll
            for (int i = 0; i < 6; ++i) { v[i] = t[(lane + 64 * i) * 33 + tl]; s += v[i]; }
#pragma unroll
            for (int o = 32; o; o >>= 1) s += __shfl_xor(s, o, 64);
            float mu = s * (1.f / DIM);
            float s2 = 0.f;
#pragma unroll
            for (int i = 0; i < 6; ++i) { float d = v[i] - mu; s2 += d * d; }
#pragma unroll
            for (int o = 32; o; o >>= 1) s2 += __shfl_xor(s2, o, 64);
            float r = rsqrtf(s2 * (1.f / DIM) + 1e-6f);
            size_t tok = (size_t)b * NTOK + n0 + tl;
#pragma unroll
            for (int i = 0; i < 6; ++i) {
                int c = lane + 64 * i;
                hOut[tok * DIM + c] = v[i];
                y[tok * DIM + c] = __float2bfloat16((v[i] - mu) * r * g[c] + bta[c]);
            }
        }
    }
}

// ---------------------------------------------------------------------------
// qkv_gemm_xpose: blocks 0..1151 = QKV 64x64 GEMM (BK=64, XCD-swizzled,
// Q,K -> C[M,1152]; V -> permuted VT). Blocks 1152..2447 = Wo/W1/W2
// cast+transpose tiles (backfill the GEMM's latency gaps; R11 technique).
// ---------------------------------------------------------------------------
__global__ __launch_bounds__(256) void qkv_gemm_xpose(
    const __hip_bfloat16* __restrict__ A,    // bufNb [4096][384]
    const __hip_bfloat16* __restrict__ BT,   // WqkvT [1152][384]
    __hip_bfloat16* __restrict__ Cout,       // bf16 [4096][1152]
    __hip_bfloat16* __restrict__ vtout,      // bf16 [16][48][2048]
    const float* __restrict__ Wo, const float* __restrict__ W1,
    const float* __restrict__ W2,
    __hip_bfloat16* __restrict__ WoT, __hip_bfloat16* __restrict__ W1T,
    __hip_bfloat16* __restrict__ W2T) {
    __shared__ __align__(16) u16 As[2][64 * 32];
    __shared__ __align__(16) u16 Bs[2][64 * 32];
    const int lid = blockIdx.x;
    const int tid = threadIdx.x;
    if (lid < 1152) {
        const int swz = (lid & 7) * 144 + (lid >> 3);   // 1152%8==0, bijective
        const int bx = swz % 18, by = swz / 18;
        const int bm = by * 64, bn = bx * 64;
        const int K = DIM;
        int w = tid >> 6, l = tid & 63;
        int m0 = (w >> 1) * 32, n0 = (w & 1) * 32;
        int lm = l & 15, ksel = l >> 4;

        int row = tid >> 2, c16 = tid & 3;
        const __hip_bfloat16* ga = A  + (size_t)(bm + row) * K + c16 * 8;
        const __hip_bfloat16* gb = BT + (size_t)(bn + row) * K + c16 * 8;

        f32x4 acc[2][2] = {};
        for (int k0 = 0; k0 < K; k0 += 64) {
#pragma unroll
            for (int c = 0; c < 2; ++c) {
                load_lds16(ga + k0 + c * 32, &As[c][tid * 8]);
                load_lds16(gb + k0 + c * 32, &Bs[c][tid * 8]);
            }
            __syncthreads();
#pragma unroll
            for (int kk = 0; kk < 2; ++kk) {
                bf16x8 af0 = *(const bf16x8*)&As[kk][(m0 +      lm) * 32 + ksel * 8];
                bf16x8 af1 = *(const bf16x8*)&As[kk][(m0 + 16 + lm) * 32 + ksel * 8];
                bf16x8 bf0 = *(const bf16x8*)&Bs[kk][(n0 +      lm) * 32 + ksel * 8];
                bf16x8 bf1 = *(const bf16x8*)&Bs[kk][(n0 + 16 + lm) * 32 + ksel * 8];
                acc[0][0] = __builtin_amdgcn_mfma_f32_16x16x32_bf16(af0, bf0, acc[0][0], 0, 0, 0);
                acc[0][1] = __builtin_amdgcn_mfma_f32_16x16x32_bf16(af0, bf1, acc[0][1], 0, 0, 0);
                acc[1][0] = __builtin_amdgcn_mfma_f32_16x16x32_bf16(af1, bf0, acc[1][0], 0, 0, 0);
                acc[1][1] = __builtin_amdgcn_mfma_f32_16x16x32_bf16(af1, bf1, acc[1][1], 0, 0, 0);
            }
            __syncthreads();
        }
#pragma unroll
        for (int i = 0; i < 2; ++i)
#pragma unroll
            for (int j = 0; j < 2; ++j)
#pragma unroll
                for (int r = 0; r < 4; ++r) {
                    int rg = bm + m0 + i * 16 + ksel * 4 + r;
                    int cg = bn + n0 + j * 16 + lm;
                    float v = acc[i][j][r];
                    if (cg < 768) {
                        Cout[(size_t)rg * 1152 + cg] = __float2bfloat16(v);
                    } else {
                        int c = cg - 768, hh = c / 48, dd = c - hh * 48;
                        int bb = rg >> 11, n = rg & (NTOK - 1);
                        int kk = n & 127;
                        int pos = ((kk >> 6) << 6) + ((kk & 15) << 2) + ((kk >> 4) & 3);
                        vtout[((size_t)(bb * NHEAD + hh) * 48 + dd) * 2048
                              + (n & ~127) + pos] = __float2bfloat16(v);
                    }
                }
    } else {
        float (*t)[33] = (float(*)[33])As;   // 4.2 KB < 8 KB
        int id = lid - 1152;
        const float* src; __hip_bfloat16* dst; int R, C;
        if (id < 144)      {            src = Wo; dst = WoT; R = 384;  C = 384; }
        else if (id < 720) { id -= 144; src = W1; dst = W1T; R = 384;  C = 1536; }
        else               { id -= 720; src = W2; dst = W2T; R = 1536; C = 384; }
        int tc = C / 32;
        int i0 = (id / tc) * 32, j0 = (id % tc) * 32;
        int tx = tid & 31, ty = tid >> 5;
#pragma unroll
        for (int k = 0; k < 32; k += 8)
            t[ty + k][tx] = src[(size_t)(i0 + ty + k) * C + j0 + tx];
        __syncthreads();
#pragma unroll
        for (int k = 0; k < 32; k += 8)
            dst[(size_t)(j0 + ty + k) * R + i0 + tx] = __float2bfloat16(t[tx][ty + k]);
    }
}

// ---------------------------------------------------------------------------
// 64x64 bf16 MFMA GEMM (BK=64, single-buffered) — used for W1 (MLP up).
// XCD-swizzled block id (T1, bijective: grid %8==0).
// ---------------------------------------------------------------------------
template<int BK, bool GELU>
__global__ __launch_bounds__(256) void gemm_mfma(
    const __hip_bfloat16* __restrict__ A,    // [M,K]
    const __hip_bfloat16* __restrict__ BT,   // [N,K]
    const float* __restrict__ bias,
    __hip_bfloat16* __restrict__ Cout,
    int M, int N, int K) {
    constexpr int NC = BK / 32;
    __shared__ __align__(16) u16 As[NC][64 * 32];
    __shared__ __align__(16) u16 Bs[NC][64 * 32];
    const int nwg = gridDim.x * gridDim.y;
    const int lid = blockIdx.y * gridDim.x + blockIdx.x;
    const int swz = (lid & 7) * (nwg >> 3) + (lid >> 3);
    const int bx = swz % gridDim.x, by = swz / gridDim.x;
    int bm = by * 64, bn = bx * 64;
    int tid = threadIdx.x;
    int w = tid >> 6, l = tid & 63;
    int m0 = (w >> 1) * 32, n0 = (w & 1) * 32;
    int lm = l & 15, ksel = l >> 4;

    int row = tid >> 2, c16 = tid & 3;
    const __hip_bfloat16* ga = A  + (size_t)(bm + row) * K + c16 * 8;
    const __hip_bfloat16* gb = BT + (size_t)(bn + row) * K + c16 * 8;

    f32x4 acc[2][2] = {};
    for (int k0 = 0; k0 < K; k0 += BK) {
#pragma unroll
        for (int c = 0; c < NC; ++c) {
            load_lds16(ga + k0 + c * 32, &As[c][tid * 8]);
            load_lds16(gb + k0 + c * 32, &Bs[c][tid * 8]);
        }
        __syncthreads();
#pragma unroll
        for (int kk = 0; kk < NC; ++kk) {
            bf16x8 af0 = *(const bf16x8*)&As[kk][(m0 +      lm) * 32 + ksel * 8];
            bf16x8 af1 = *(const bf16x8*)&As[kk][(m0 + 16 + lm) * 32 + ksel * 8];
            bf16x8 bf0 = *(const bf16x8*)&Bs[kk][(n0 +      lm) * 32 + ksel * 8];
            bf16x8 bf1 = *(const bf16x8*)&Bs[kk][(n0 + 16 + lm) * 32 + ksel * 8];
            acc[0][0] = __builtin_amdgcn_mfma_f32_16x16x32_bf16(af0, bf0, acc[0][0], 0, 0, 0);
            acc[0][1] = __builtin_amdgcn_mfma_f32_16x16x32_bf16(af0, bf1, acc[0][1], 0, 0, 0);
            acc[1][0] = __builtin_amdgcn_mfma_f32_16x16x32_bf16(af1, bf0, acc[1][0], 0, 0, 0);
            acc[1][1] = __builtin_amdgcn_mfma_f32_16x16x32_bf16(af1, bf1, acc[1][1], 0, 0, 0);
        }
        __syncthreads();
    }

#pragma unroll
    for (int i = 0; i < 2; ++i)
#pragma unroll
        for (int j = 0; j < 2; ++j)
#pragma unroll
            for (int r = 0; r < 4; ++r) {
                int rg = bm + m0 + i * 16 + ksel * 4 + r;
                int cg = bn + n0 + j * 16 + lm;
                float v = acc[i][j][r];
                if (bias) v += bias[cg];
                if (GELU) v = 0.5f * v * (1.f + erff(v * 0.7071067811865475f));
                Cout[(size_t)rg * N + cg] = __float2bfloat16(v);
            }
}

// ---------------------------------------------------------------------------
// w2_gemm: MLP down + bias + residual -> transposed f32 out. 32x64 tiles ->
// 768 blocks = 3 balanced rounds/CU. BK=128; rule-21 XOR granule swizzle.
// (R12 champion structure.)
// ---------------------------------------------------------------------------
__global__ __launch_bounds__(256) void w2_gemm(
    const __hip_bfloat16* __restrict__ A,    // bufHIDb [4096][1536]
    const __hip_bfloat16* __restrict__ BT,   // W2T [384][1536]
    const float* __restrict__ bias,          // b2m
    const float* __restrict__ res,           // bufH f32 [4096][384]
    float* __restrict__ outp) {              // out f32 [2][384][2048]
    __shared__ __align__(16) u16 As[32 * 128];   //  8 KB
    __shared__ __align__(16) u16 Bs[64 * 128];   // 16 KB
    __shared__ float ct[32 * 65];                // 8.3 KB
    const int K = HIDDEN, N = DIM;
    const int nwg = gridDim.x * gridDim.y;       // 768
    const int lid = blockIdx.y * gridDim.x + blockIdx.x;
    const int swz = (lid & 7) * (nwg >> 3) + (lid >> 3);
    const int bx = swz % gridDim.x, by = swz / gridDim.x;
    const int bm = by * 32, bn = bx * 64;
    const int tid = threadIdx.x;
    const int w = tid >> 6, l = tid & 63;
    const int n0 = w * 16;
    const int lm = l & 15, ksel = l >> 4;
    const int xr = lm & 7;                       // read-side granule XOR

    f32x4 acc[2] = {};
    for (int k0 = 0; k0 < K; k0 += 128) {
#pragma unroll
        for (int i = 0; i < 2; ++i) {
            int idx = tid + i * 256;
            int row = idx >> 4, p = idx & 15;
            int g = p ^ (row & 7);
            load_lds16(A + (size_t)(bm + row) * K + k0 + g * 8, (char*)As + idx * 16);
        }
#pragma unroll
        for (int i = 0; i < 4; ++i) {
            int idx = tid + i * 256;
            int row = idx >> 4, p = idx & 15;
            int g = p ^ (row & 7);
            load_lds16(BT + (size_t)(bn + row) * K + k0 + g * 8, (char*)Bs + idx * 16);
        }
        __syncthreads();
#pragma unroll
        for (int kk = 0; kk < 4; ++kk) {
            int gq = ((kk * 4 + ksel) ^ xr) * 8;
            bf16x8 af0 = *(const bf16x8*)&As[lm        * 128 + gq];
            bf16x8 af1 = *(const bf16x8*)&As[(16 + lm) * 128 + gq];
            bf16x8 bf  = *(const bf16x8*)&Bs[(n0 + lm) * 128 + gq];
            acc[0] = __builtin_amdgcn_mfma_f32_16x16x32_bf16(af0, bf, acc[0], 0, 0, 0);
            acc[1] = __builtin_amdgcn_mfma_f32_16x16x32_bf16(af1, bf, acc[1], 0, 0, 0);
        }
        __syncthreads();
    }

#pragma unroll
    for (int m = 0; m < 2; ++m)
#pragma unroll
        for (int r = 0; r < 4; ++r) {
            int ml = m * 16 + ksel * 4 + r;
            int cl = n0 + lm;
            float v = acc[m][r] + bias[bn + cl]
                    + res[(size_t)(bm + ml) * N + bn + cl];
            ct[ml * 65 + cl] = v;
        }
    __syncthreads();
    int bb = bm >> 11, nb = bm & (NTOK - 1);
    float* op = outp + (size_t)bb * DIM * NTOK + nb;
#pragma unroll
    for (int cc = w * 2; cc < 64; cc += 8) {
        int cl = cc + (l >> 5), rw = l & 31;
        op[(size_t)(bn + cl) * NTOK + rw] = ct[rw * 65 + cl];
    }
}

// ---------------------------------------------------------------------------
// wo_ln: fused output-projection + bias + residual + LayerNorm2 (R6 champion:
// BK=64, single-buffered). Tile 16M x 384N, grid 256 = 1/CU. XOR granule
// swizzle g^(row&7) (rule-21).
// ---------------------------------------------------------------------------
__global__ __launch_bounds__(256) void wo_ln(
    const __hip_bfloat16* __restrict__ A,    // bufAb [4096][384]
    const __hip_bfloat16* __restrict__ BT,   // WoT   [384][384]
    const float* __restrict__ bo,
    const float* __restrict__ g2, const float* __restrict__ b2,
    float* __restrict__ h,                   // bufH in (old) / out (new)
    __hip_bfloat16* __restrict__ y) {        // bufNb
    __shared__ __align__(16) u16 As[16 * 64];    //  2 KB
    __shared__ __align__(16) u16 Bs[384 * 64];   // 48 KB
    __shared__ float red[16 * 8];
    const int r0 = blockIdx.x * 16;
    const int tid = threadIdx.x;
    const int w = tid >> 6, l = tid & 63, lm = l & 15, quad = l >> 4;

    const int arow = tid >> 3;
    const int ag = (tid & 7) ^ (arow & 7);
    const __hip_bfloat16* gaA = A + (size_t)(r0 + arow) * DIM + ag * 8;
    const int xr = lm & 7;                       // read-side granule XOR

    f32x4 acc[6] = {};
    for (int k0 = 0; k0 < DIM; k0 += 64) {
        if (tid < 128) load_lds16(gaA + k0, (char*)As + tid * 16);
#pragma unroll
        for (int i = 0; i < 12; ++i) {
            int idx = tid + i * 256;             // 0..3071
            int brow = idx >> 3;
            int bg = (idx & 7) ^ (brow & 7);
            load_lds16(BT + (size_t)brow * DIM + k0 + bg * 8, (char*)Bs + idx * 16);
        }
        __syncthreads();
#pragma unroll
        for (int kk = 0; kk < 2; ++kk) {
            int goff = ((kk * 4 + quad) ^ xr) * 8;
            bf16x8 af = *(const bf16x8*)&As[lm * 64 + goff];
#pragma unroll
            for (int n = 0; n < 6; ++n) {
                bf16x8 bf = *(const bf16x8*)&Bs[(w * 96 + n * 16 + lm) * 64 + goff];
                acc[n] = __builtin_amdgcn_mfma_f32_16x16x32_bf16(af, bf, acc[n], 0, 0, 0);
            }
        }
        __syncthreads();
    }

    float vv[6][4];
    float s1[4] = {0.f, 0.f, 0.f, 0.f}, s2[4] = {0.f, 0.f, 0.f, 0.f};
#pragma unroll
    for (int r = 0; r < 4; ++r) {
        int rg = r0 + quad * 4 + r;
#pragma unroll
        for (int n = 0; n < 6; ++n) {
            int cg = w * 96 + n * 16 + lm;
            float v = acc[n][r] + bo[cg] + h[(size_t)rg * DIM + cg];
            vv[n][r] = v;
            s1[r] += v;
            s2[r] += v * v;
            h[(size_t)rg * DIM + cg] = v;        // new residual state
        }
    }
#pragma unroll
    for (int r = 0; r < 4; ++r) {
#pragma unroll
        for (int o = 8; o; o >>= 1) {
            s1[r] += __shfl_xor(s1[r], o, 64);
            s2[r] += __shfl_xor(s2[r], o, 64);
        }
        if (lm == 0) {
            red[(quad * 4 + r) * 8 + w * 2]     = s1[r];
            red[(quad * 4 + r) * 8 + w * 2 + 1] = s2[r];
        }
    }
    __syncthreads();
#pragma unroll
    for (int r = 0; r < 4; ++r) {
        int lr = quad * 4 + r;
        float S1 = red[lr * 8] + red[lr * 8 + 2] + red[lr * 8 + 4] + red[lr * 8 + 6];
        float S2 = red[lr * 8 + 1] + red[lr * 8 + 3] + red[lr * 8 + 5] + red[lr * 8 + 7];
        float mu = S1 * (1.f / DIM);
        float var = S2 * (1.f / DIM) - mu * mu;
        float rstd = rsqrtf(var + 1e-6f);
        int rg = r0 + lr;
#pragma unroll
        for (int n = 0; n < 6; ++n) {
            int cg = w * 96 + n * 16 + lm;
            y[(size_t)rg * DIM + cg] =
                __float2bfloat16((vv[n][r] - mu) * rstd * g2[cg] + b2[cg]);
        }
    }
}

// ---------------------------------------------------------------------------
// bf16 MFMA flash attention, QBLK=128 @ 1024 threads (16 waves): grid 256 =
// exactly 1 block/CU with 16 waves/CU = SAME wave occupancy as the old
// 2x512 config, but each K/V tile staged once serves 128 q-rows (was 64) ->
// K/V global + LDS staging traffic HALVES; barriers per q-row halve.
// Wave w: q-chunk qc=w>>1 (16 rows of 128), key-half kh=w&1 (64 of 128 keys).
// T14 reg-prefetch + XCD swizzle retained. Merge scratch uses PQ (34.8 KB
// >= 32 KB needed). LDS total 64.8 KB.
// ---------------------------------------------------------------------------
#define ATK 128
#define PSTR 136   // row stride in u16; rows 16B-aligned
__global__ __launch_bounds__(1024, 4) void attn_mfma(
    const u16* __restrict__ qkv,             // bf16 [TOKS][1152] (Q,K valid)
    const u16* __restrict__ vt,              // bf16 [16][48][2048] (permuted keys)
    __hip_bfloat16* __restrict__ outp) {     // bf16 [TOKS][DIM]
    __shared__ __align__(16) u16 PQ[128 * PSTR];  // Q (stride 72) then P; merge scratch
    __shared__ __align__(16) u16 Ks[128 * 72];
    __shared__ __align__(16) u16 Vs[48 * PSTR];
    const int lid = (blockIdx.z * NHEAD + blockIdx.y) * (NTOK / 128) + blockIdx.x;
    const int swz = (lid & 7) * 32 + (lid >> 3);  // 256 blocks, bijective
    const int q0 = (swz & 15) * 128;
    const int h = (swz >> 4) & 7, b = swz >> 7;
    const int tid = threadIdx.x;
    const int w = tid >> 6, l = tid & 63, lm = l & 15, quad = l >> 4;
    const int qc = w >> 1, kh = w & 1;            // qc 0..7

    // zero pads: Q cols 48-63 (128 rows x 2 uint4), K cols 48-63 (128 x 2)
    if (tid < 256) {
        int r = tid >> 1, c = tid & 1;
        *(uint4*)&PQ[r * 72 + 48 + c * 8] = uint4{0, 0, 0, 0};
    } else if (tid < 512) {
        int t2 = tid - 256;
        int r = t2 >> 1, c = t2 & 1;
        *(uint4*)&Ks[r * 72 + 48 + c * 8] = uint4{0, 0, 0, 0};
    }
    // stage Q tile (128 rows x 48) at stride 72: 768 uint4, threads 0..767
    const u16* qbase = qkv + (size_t)(b * NTOK + q0) * 1152 + h * 48;
    if (tid < 768) {
        int r = tid / 6, c = tid % 6;
        *(uint4*)&PQ[r * 72 + c * 8] = *(const uint4*)(qbase + (size_t)r * 1152 + c * 8);
    }

    const u16* kbase = qkv + (size_t)(b * NTOK) * 1152 + 384 + h * 48;
    const u16* vbase = vt + (size_t)(b * NHEAD + h) * 48 * 2048;
    const float sc2 = 0.14433756729740643f * 1.4426950408889634f;  // scale*log2e

    // K/V staging: 1536 uint4/tile. Entry p0 = idx tid (all 1024 threads);
    // entry p1 = idx tid+1024 (threads 0..511). idx<768 -> K[row=idx/6,
    // col=idx%6]; idx>=768 -> V[d=(idx-768)>>4, c=(idx-768)&15].
    const bool isK0 = tid < 768;
    const int kr0 = tid / 6, kc0 = tid % 6;            // valid when isK0
    const int j0v = tid - 768;                          // valid when !isK0
    const int vd0 = j0v >> 4, vc0 = j0v & 15;
    const bool two = tid < 512;
    const int j1v = tid + 256;                          // idx1-768 = tid+256
    const int vd1 = j1v >> 4, vc1 = j1v & 15;
    uint4 p0, p1;

    // prefetch + commit tile 0
    if (isK0) p0 = *(const uint4*)(kbase + (size_t)kr0 * 1152 + kc0 * 8);
    else      p0 = *(const uint4*)(vbase + (size_t)vd0 * 2048 + vc0 * 8);
    if (two)  p1 = *(const uint4*)(vbase + (size_t)vd1 * 2048 + vc1 * 8);
    if (isK0) *(uint4*)&Ks[kr0 * 72 + kc0 * 8] = p0;
    else      *(uint4*)&Vs[vd0 * PSTR + vc0 * 8] = p0;
    if (two)  *(uint4*)&Vs[vd1 * PSTR + vc1 * 8] = p1;
    __syncthreads();

    bf16x8 aq0 = *(const bf16x8*)&PQ[(qc * 16 + lm) * 72 +  0 + quad * 8];
    bf16x8 aq1 = *(const bf16x8*)&PQ[(qc * 16 + lm) * 72 + 32 + quad * 8];

    float l_i[4] = {0.f, 0.f, 0.f, 0.f};
    f32x4 o_acc[3] = {};

    for (int kt = 0; kt < NTOK / ATK; ++kt) {
        __syncthreads();   // iter 0: Q-frag reads done before P writes;
                           // iter >0: commit visible + prior reads done
        if (kt > 0) {      // commit tile kt (prefetched last iteration)
            if (isK0) *(uint4*)&Ks[kr0 * 72 + kc0 * 8] = p0;
            else      *(uint4*)&Vs[vd0 * PSTR + vc0 * 8] = p0;
            if (two)  *(uint4*)&Vs[vd1 * PSTR + vc1 * 8] = p1;
            __syncthreads();
        }
        // prefetch tile kt+1 (latency hides under compute below)
        if (kt + 1 < NTOK / ATK) {
            const u16* kb = kbase + (size_t)(kt + 1) * ATK * 1152;
            const u16* vb = vbase + (size_t)(kt + 1) * ATK;
            if (isK0) p0 = *(const uint4*)(kb + (size_t)kr0 * 1152 + kc0 * 8);
            else      p0 = *(const uint4*)(vb + (size_t)vd0 * 2048 + vc0 * 8);
            if (two)  p1 = *(const uint4*)(vb + (size_t)vd1 * 2048 + vc1 * 8);
        }

        // S = Q K^T for this wave's 4 key-subtiles
        f32x4 s[4];
#pragma unroll
        for (int ntp = 0; ntp < 4; ++ntp) {
            int nt = kh * 4 + ntp;
            bf16x8 kf0 = *(const bf16x8*)&Ks[(nt * 16 + lm) * 72 +  0 + quad * 8];
            bf16x8 kf1 = *(const bf16x8*)&Ks[(nt * 16 + lm) * 72 + 32 + quad * 8];
            f32x4 t = {};
            t = __builtin_amdgcn_mfma_f32_16x16x32_bf16(aq0, kf0, t, 0, 0, 0);
            t = __builtin_amdgcn_mfma_f32_16x16x32_bf16(aq1, kf1, t, 0, 0, 0);
            s[ntp] = t;
        }

        // P = exp2(S*sc2); wave-private row-segment of PQ
#pragma unroll
        for (int r = 0; r < 4; ++r) {
            u16 pr[4];
#pragma unroll
            for (int ntp = 0; ntp < 4; ++ntp) {
                float p = exp2f(s[ntp][r] * sc2);
                l_i[r] += p;
                bfu cv; cv.h = __float2bfloat16(p);
                pr[ntp] = cv.u;
            }
            *(uint2*)&PQ[(qc * 16 + quad * 4 + r) * PSTR + kh * 64 + lm * 4] =
                *(const uint2*)pr;
        }

        // O += P V over this wave's 64 stored positions
#pragma unroll
        for (int ksp = 0; ksp < 2; ++ksp) {
            int ks = kh * 2 + ksp;
            bf16x8 pf = *(const bf16x8*)&PQ[(qc * 16 + lm) * PSTR + ks * 32 + quad * 8];
#pragma unroll
            for (int nt = 0; nt < 3; ++nt) {
                bf16x8 vf = *(const bf16x8*)&Vs[(nt * 16 + lm) * PSTR + ks * 32 + quad * 8];
                o_acc[nt] = __builtin_amdgcn_mfma_f32_16x16x32_bf16(pf, vf, o_acc[nt], 0, 0, 0);
            }
        }
    }

    // merge kh=0 / kh=1 partials via LDS (reuse PQ as f32 scratch: 8 q-chunks
    // x 64 lanes x 16 f32 = 32 KB <= 34.8 KB)
    __syncthreads();
    float* red = (float*)PQ;
    if (kh == 1) {
        f32x4* base = (f32x4*)&red[(qc * 64 + l) * 16];
        base[0] = o_acc[0]; base[1] = o_acc[1]; base[2] = o_acc[2];
        f32x4 lv; lv[0] = l_i[0]; lv[1] = l_i[1]; lv[2] = l_i[2]; lv[3] = l_i[3];
        base[3] = lv;
    }
    __syncthreads();
    if (kh == 0) {
        f32x4* base = (f32x4*)&red[(qc * 64 + l) * 16];
        o_acc[0] += base[0]; o_acc[1] += base[1]; o_acc[2] += base[2];
        f32x4 lv = base[3];
#pragma unroll
        for (int r = 0; r < 4; ++r) {
            float lsum = l_i[r] + lv[r];
#pragma unroll
            for (int o = 8; o; o >>= 1) lsum += __shfl_xor(lsum, o, 64);
            float inv = 1.f / lsum;
#pragma unroll
            for (int nt = 0; nt < 3; ++nt)
                outp[(size_t)(b * NTOK + q0 + qc * 16 + quad * 4 + r) * DIM
                     + h * 48 + nt * 16 + lm]
                    = __float2bfloat16(o_acc[nt][r] * inv);
        }
    }
}

// ---------------------------------------------------------------------------
extern "C" void kernel_launch(void* const* d_in, const int* in_sizes, int n_in,
                              void* d_out, int out_size, void* d_ws, size_t ws_size,
                              hipStream_t stream) {
    const float* x    = (const float*)d_in[0];
    const float* g1   = (const float*)d_in[1];
    const float* b1   = (const float*)d_in[2];
    const float* Wqkv = (const float*)d_in[3];
    const float* Wo   = (const float*)d_in[4];
    const float* bo   = (const float*)d_in[5];
    const float* g2   = (const float*)d_in[6];
    const float* b2   = (const float*)d_in[7];
    const float* W1   = (const float*)d_in[8];
    const float* b1m  = (const float*)d_in[9];
    const float* W2   = (const float*)d_in[10];
    const float* b2m  = (const float*)d_in[11];
    float* out = (float*)d_out;

    char* p = (char*)d_ws;
    float* bufH = (float*)p;                       p += (size_t)TOKS * DIM * 4;      // f32 [4096,384]
    char* qkvp = p;
    __hip_bfloat16* bufQKVb = (__hip_bfloat16*)p;  p += (size_t)TOKS * 3 * DIM * 2;  // bf16 [4096,1152]
    __hip_bfloat16* bufVT   = (__hip_bfloat16*)p;  p += (size_t)TOKS * DIM * 2;      // bf16 [16,48,2048]
    __hip_bfloat16* bufNb   = (__hip_bfloat16*)p;  p += (size_t)TOKS * DIM * 2;      // bf16 [4096,384]
    __hip_bfloat16* bufAb   = (__hip_bfloat16*)p;  p += (size_t)TOKS * DIM * 2;      // bf16 [4096,384]
    __hip_bfloat16* WqkvT   = (__hip_bfloat16*)p;  p += (size_t)3 * DIM * DIM * 2;   // [1152,384]
    __hip_bfloat16* WoT     = (__hip_bfloat16*)p;  p += (size_t)DIM * DIM * 2;       // [384,384]
    __hip_bfloat16* W1T     = (__hip_bfloat16*)p;  p += (size_t)HIDDEN * DIM * 2;    // [1536,384]
    __hip_bfloat16* W2T     = (__hip_bfloat16*)p;  p += (size_t)DIM * HIDDEN * 2;    // [384,1536]
    __hip_bfloat16* bufHIDb = (__hip_bfloat16*)qkvp;  // bf16 [4096,1536] overlays QKV+VT

    // 0. Wqkv transpose + input transpose/LN1 (critical path only)
    prep<<<432 + 128, 256, 0, stream>>>(Wqkv, WqkvT, x, g1, b1, bufH, bufNb);
    // 1. QKV projection (BK=64, swizzled) + Wo/W1/W2 transposes backfilled
    qkv_gemm_xpose<<<1152 + 1296, 256, 0, stream>>>(
        bufNb, WqkvT, bufQKVb, bufVT, Wo, W1, W2, WoT, W1T, W2T);
    // 2. MFMA flash attention, QBLK=128 @ 1024 thr (256 blocks = 1/CU,
    //    16 waves/CU — same occupancy, half the K/V staging traffic)
    attn_mfma<<<dim3(NTOK / 128, NHEAD, BATCH), 1024, 0, stream>>>(
        (const u16*)bufQKVb, (const u16*)bufVT, bufAb);
    // 3. fused output projection + bias + residual + LN2 (R6 champion)
    wo_ln<<<TOKS / 16, 256, 0, stream>>>(bufAb, WoT, bo, g2, b2, bufH, bufNb);
    // 4. MLP up + GELU -> bf16 hidden (BK=64, 8 blocks/CU)
    gemm_mfma<64, true><<<dim3(HIDDEN / 64, TOKS / 64), 256, 0, stream>>>(
        bufNb, W1T, b1m, bufHIDb, TOKS, HIDDEN, DIM);
    // 5. MLP down + bias + residual -> out (32x64 tiles, 768 blocks = 3/CU)
    w2_gemm<<<dim3(DIM / 64, TOKS / 32), 256, 0, stream>>>(
        bufHIDb, W2T, b2m, bufH, out);
}